// Round 4
// baseline (3626.591 us; speedup 1.0000x reference)
//
#include <hip/hip_runtime.h>
#include <hip/hip_bf16.h>
#include <math.h>

// ---------------- problem constants ----------------
#define B_ 8192
#define T_ 223
#define D_ 7
#define H_ 128
#define G_ 512      // 4*H
#define E_ 50
#define O_ 29
#define A_ 9
#define TD_ (T_*D_)     // 1561
#define NB 16           // batch rows per block (main kernel) -> grid 512, 2 blocks/CU
#define NTHR 512
#define MB 8            // batch rows per block (head kernel)

// ---------------- workspace layout (float offsets) ----------------
#define WS_TACC  0                            // [T][2] = (x_loss numerator_t, msum_t)
#define WS_ACC   (WS_TACC + 2*T_)             // y_loss raw sum (1 float)
#define WS_WCATT (WS_ACC + 1)                 // [178][128] transposed W_cat
#define WS_HFIN  (WS_WCATT + 178*H_)          // final h, [B][128] fp32

// ---------------- output layout (floats) ----------------
#define OUT_YH  3
#define OUT_IMP (OUT_YH + B_*O_)              // 237571
#define OUT_LAB (OUT_IMP + B_*T_*D_)          // 13025283

typedef __attribute__((ext_vector_type(8))) short short8;   // 8 bf16 = 4 VGPRs
typedef __attribute__((ext_vector_type(4))) float floatx4;
#define MFMA16(Av,Bv,Cv) __builtin_amdgcn_mfma_f32_16x16x32_bf16((Av),(Bv),(Cv),0,0,0)

__device__ __forceinline__ unsigned short f2bf(float f) {   // RNE fp32->bf16
    __hip_bfloat16 h = __float2bfloat16(f);
    return __builtin_bit_cast(unsigned short, h);
}
__device__ __forceinline__ float bf2f(unsigned short s) {
    unsigned int u = ((unsigned int)s) << 16;
    return __builtin_bit_cast(float, u);
}
__device__ __forceinline__ float rcp_(float x)  { return __builtin_amdgcn_rcpf(x); }
__device__ __forceinline__ float sigm(float x)  { return rcp_(1.f + __expf(-x)); }
__device__ __forceinline__ float tanh_(float x) { return 1.f - 2.f*rcp_(1.f + __expf(2.f*x)); }

// ================= prep: W_cat transpose + zero accumulators =================
__global__ void rits_prep(const float* __restrict__ W_cat, float* __restrict__ ws)
{
    int idx = blockIdx.x * 256 + threadIdx.x;
    if (idx < H_*178) {                      // W_cat [128][178] -> [178][128]
        int j = idx / 178, k = idx - j*178;
        ws[WS_WCATT + k*H_ + j] = W_cat[idx];
    }
    if (idx < 2*T_ + 1) ws[WS_TACC + idx] = 0.f;   // covers WS_TACC + WS_ACC
}

// ================= main scan kernel (MFMA) =================
// D[gate j][batch b] = sum_k W_ext[j][k] * hext[b][k]
// A-frags (weights) persistent in VGPRs; B-frags (h / interleaved c_c,m) from LDS.
// Wave w owns gate M-tiles {w, 8+w, 16+w, 24+w} (one per i/f/g/o quadrant) so
// each lane's C rows give i,f,g,o for the SAME hidden j = w*16+quad*4+r.
__global__ __launch_bounds__(NTHR, 4) void rits_main(
    const float* __restrict__ values, const float* __restrict__ masks, const float* __restrict__ deltas,
    const float* __restrict__ W_td_h, const float* __restrict__ b_td_h,
    const float* __restrict__ W_td_x, const float* __restrict__ b_td_x,
    const float* __restrict__ W_hist, const float* __restrict__ b_hist,
    const float* __restrict__ W_feat, const float* __restrict__ b_feat,
    const float* __restrict__ W_comb, const float* __restrict__ b_comb,
    const float* __restrict__ W_ih, const float* __restrict__ W_hh,
    const float* __restrict__ b_ih, const float* __restrict__ b_hh,
    float* __restrict__ ws, float* __restrict__ out)
{
    // B-operand buffer: rows=batch(16), cols bf16: 0..127=h,
    // 128+2i=c_c[i], 129+2i=m[i] (i<7), 142..159=0. Row stride 168 bf16 = 336B.
    __shared__ __attribute__((aligned(16))) unsigned short hbuf[NB*168];
    __shared__ __attribute__((aligned(16))) unsigned short dbuf[NB*72];      // d(t+1) bf16, cols 7..31=0
    __shared__ __attribute__((aligned(16))) unsigned short whis_lds[16*136]; // W_hist bf16, rows 7..15=0
    __shared__ float xs[NB*8], msh[NB*8], dsl[NB*8];
    __shared__ float xh_l[NB*8], xc_l[NB*8], gx_l[NB*8];
    __shared__ float bhist_l[8], tdx_l[8], btdx_l[8];
    __shared__ float impbuf[NB*16*7];       // 16-step imputation buffer (fp32)

    const int tid  = threadIdx.x;
    const int b0   = blockIdx.x * NB;
    const int lane = tid & 63;
    const int w    = tid >> 6;      // wave 0..7
    const int quad = lane >> 4;
    const int l15  = lane & 15;

    // ---- one-time LDS init ----
    for (int i = tid; i < NB*168; i += NTHR) hbuf[i] = 0;
    for (int i = tid; i < NB*72;  i += NTHR) dbuf[i] = 0;
    for (int i = tid; i < 16*136; i += NTHR) {
        int r = i / 136, c = i - r*136;
        whis_lds[i] = (r < 7 && c < 128) ? f2bf(W_hist[r*H_ + c]) : 0;
    }
    if (tid < 8) {
        bhist_l[tid] = (tid < 7) ? b_hist[tid] : 0.f;
        tdx_l[tid]   = (tid < 7) ? W_td_x[tid*D_ + tid] : 0.f;
        btdx_l[tid]  = (tid < 7) ? b_td_x[tid] : 0.f;
    }

    // ---- persistent weight fragments (per lane) ----
    short8 whhf[4][4];   // [gate c][kstep]  A[j=l15 of tile][k=quad*8+e]
    short8 winf[4];      // ext kstep, interleaved: k=2i -> W_ih[j][i], k=2i+1 -> W_ih[j][7+i]
    short8 wtdf;         // W_td_h frag (j = w*16+l15, k<7)
    float  biasg_r[4][4];
    float  btdh_r[4];
    {
        union UU { short8 v; unsigned short u[8]; } fr;
        #pragma unroll
        for (int c = 0; c < 4; ++c) {
            const int j = (c*8 + w)*16 + l15;
            #pragma unroll
            for (int s = 0; s < 4; ++s) {
                const float* p = W_hh + j*H_ + s*32 + quad*8;
                #pragma unroll
                for (int e = 0; e < 8; ++e) fr.u[e] = f2bf(p[e]);
                whhf[c][s] = fr.v;
            }
            #pragma unroll
            for (int e = 0; e < 8; ++e) {
                int k = quad*8 + e;
                fr.u[e] = (k < 14) ? f2bf(W_ih[j*14 + (k >> 1) + ((k & 1) ? 7 : 0)])
                                   : (unsigned short)0;
            }
            winf[c] = fr.v;
            #pragma unroll
            for (int r = 0; r < 4; ++r) {
                int jj = (c*8 + w)*16 + quad*4 + r;
                biasg_r[c][r] = b_ih[jj] + b_hh[jj];
            }
        }
        #pragma unroll
        for (int e = 0; e < 8; ++e) {
            int k = quad*8 + e;
            fr.u[e] = (k < 7) ? f2bf(W_td_h[(w*16 + l15)*D_ + k]) : (unsigned short)0;
        }
        wtdf = fr.v;
        #pragma unroll
        for (int r = 0; r < 4; ++r) btdh_r[r] = b_td_h[w*16 + quad*4 + r];
    }

    // ---- A3 per-thread state ----
    const bool ldr = (tid < NB*D_);               // 112 threads (waves 0-1)
    const int  lb  = tid / D_, li = tid - (tid/D_)*D_;
    float wfr[7], wcr[14], bfr = 0.f, bcr = 0.f;
    if (ldr) {
        #pragma unroll
        for (int k = 0; k < 7; ++k)  wfr[k] = (k == li) ? 0.f : W_feat[li*D_ + k];
        #pragma unroll
        for (int k = 0; k < 14; ++k) wcr[k] = W_comb[li*14 + k];
        bfr = b_feat[li];  bcr = b_comb[li];
    }

    float c_st[4] = {0,0,0,0};

    // input prefetch (regs hold step-t data at loop top)
    const long gbase = (long)(b0 + lb)*TD_ + li;
    float rx = 0.f, rm = 0.f, rd = 0.f;
    if (ldr) { rx = values[gbase]; rm = masks[gbase]; rd = deltas[gbase]; }

    for (int t = 0; t < T_; ++t) {
        if (ldr) { xs[lb*8+li] = rx; msh[lb*8+li] = rm; dsl[lb*8+li] = rd; }
        __syncthreads();                       // [S] stage + prev h-writes visible
        if (ldr && t + 1 < T_) {
            const long g = gbase + (long)(t+1)*D_;
            rx = values[g]; rm = masks[g]; rd = deltas[g];
        }

        // ---- B1: gate h-part (+ x_h on wave 7). h in hbuf is ALREADY decayed ----
        floatx4 acc[4];
        #pragma unroll
        for (int c = 0; c < 4; ++c) {
            floatx4 a = { biasg_r[c][0], biasg_r[c][1], biasg_r[c][2], biasg_r[c][3] };
            acc[c] = a;
        }
        floatx4 xh0 = {0,0,0,0};
        #pragma unroll
        for (int s = 0; s < 4; ++s) {
            short8 hb0 = *(const short8*)&hbuf[l15*168 + s*32 + quad*8];
            #pragma unroll
            for (int c = 0; c < 4; ++c)
                acc[c] = MFMA16(whhf[c][s], hb0, acc[c]);
            if (w == 7) {
                short8 wh = *(const short8*)&whis_lds[l15*136 + s*32 + quad*8];
                xh0 = MFMA16(wh, hb0, xh0);
            }
        }
        // wave 7: finish x_h, compute x_c / gamma_x, publish to LDS
        if (w == 7 && quad < 2) {
            const int b = l15;
            #pragma unroll
            for (int r = 0; r < 4; ++r) {
                const int i = quad*4 + r;
                if (i < 7) {
                    float xhv = xh0[r] + bhist_l[i];
                    float x = xs[b*8+i], m = msh[b*8+i], d = dsl[b*8+i];
                    xh_l[b*8+i] = xhv;
                    xc_l[b*8+i] = m*x + (1.f-m)*xhv;
                    gx_l[b*8+i] = __expf(-fmaxf(fmaf(d, tdx_l[i], btdx_l[i]), 0.f));
                }
            }
        }
        __syncthreads();                       // [B] x_h / x_c / gamma_x ready

        // ---- A3: z_h, alpha, c_h, c_c, imputation, loss; write ext cols + dbuf ----
        float term = 0.f, msump = 0.f;
        if (ldr) {
            const int b = lb, i = li;
            const float x = xs[b*8+i], m = msh[b*8+i];
            float zh = bfr;
            #pragma unroll
            for (int k = 0; k < 7; ++k) zh = fmaf(wfr[k], xc_l[b*8+k], zh);
            float al = bcr;
            #pragma unroll
            for (int k = 0; k < 7; ++k) al = fmaf(wcr[k],   gx_l[b*8+k], al);
            #pragma unroll
            for (int k = 0; k < 7; ++k) al = fmaf(wcr[7+k], msh[b*8+k], al);
            const float xhv = xh_l[b*8+i];
            const float ch  = al*zh + (1.f-al)*xhv;
            const float cc  = m*x + (1.f-m)*ch;
            impbuf[(b*16 + (t & 15))*7 + i] = cc;
            *(unsigned int*)&hbuf[b*168 + 128 + 2*i] =
                (unsigned int)f2bf(cc) | ((unsigned int)f2bf(m) << 16);
            dbuf[b*72 + i] = f2bf(rd);         // d(t+1) for fused decay
            term  = (fabsf(x-xhv) + fabsf(x-zh) + fabsf(x-ch)) * m;
            msump = m;
        }
        if (w < 2) {                           // per-step loss reduction (waves 0-1)
            #pragma unroll
            for (int off = 32; off > 0; off >>= 1) {
                term  += __shfl_down(term,  off, 64);
                msump += __shfl_down(msump, off, 64);
            }
            if (lane == 0) {
                atomicAdd(&ws[WS_TACC + 2*t    ], term);
                atomicAdd(&ws[WS_TACC + 2*t + 1], msump);
            }
        }
        __syncthreads();                       // [C] c_c/m ext + dbuf ready

        // ---- B2: input part ----
        {
            short8 ib0 = *(const short8*)&hbuf[l15*168 + 128 + quad*8];
            #pragma unroll
            for (int c = 0; c < 4; ++c)
                acc[c] = MFMA16(winf[c], ib0, acc[c]);
        }
        // ---- fused gamma_h(t+1) via MFMA on d(t+1) ----
        floatx4 g0 = {0,0,0,0};
        const bool dec = (t + 1 < T_);
        if (dec) {
            short8 df0 = *(const short8*)&dbuf[l15*72 + quad*8];
            floatx4 z = {0,0,0,0};
            g0 = MFMA16(wtdf, df0, z);
        }
        // ---- LSTM update; write h (pre-decayed for next step) ----
        {
            const int b = l15;
            float hv[4];
            #pragma unroll
            for (int r = 0; r < 4; ++r) {
                float ig = acc[0][r], fg = acc[1][r];
                float gv = acc[2][r], og = acc[3][r];
                float cn = sigm(fg)*c_st[r] + sigm(ig)*tanh_(gv);
                c_st[r] = cn;
                float hn = sigm(og)*tanh_(cn);
                if (dec) hn *= __expf(-fmaxf(g0[r] + btdh_r[r], 0.f));
                hv[r] = hn;
            }
            uint2 pk;
            pk.x = (unsigned int)f2bf(hv[0]) | ((unsigned int)f2bf(hv[1]) << 16);
            pk.y = (unsigned int)f2bf(hv[2]) | ((unsigned int)f2bf(hv[3]) << 16);
            *(uint2*)&hbuf[b*168 + w*16 + quad*4] = pk;
        }

        // ---- imputation flush (contiguous 28B runs, 16 steps at a time) ----
        if ((t & 15) == 15 || t == T_ - 1) {
            const int t0 = t & ~15;
            if (tid < 256) {
                const int b = tid >> 4, c16 = tid & 15;
                if (t0 + c16 <= t) {
                    float* gp = out + (size_t)OUT_IMP + (size_t)(b0+b)*TD_ + (size_t)(t0+c16)*D_;
                    const float* lp = &impbuf[(b*16 + c16)*7];
                    #pragma unroll
                    for (int e = 0; e < 7; ++e) gp[e] = lp[e];
                }
            }
        }
    }
    __syncthreads();

    // ---- final h -> workspace (fp32) ----
    for (int i = tid; i < NB*H_; i += NTHR) {
        int b = i >> 7, j = i & 127;
        ws[WS_HFIN + (size_t)(b0+b)*H_ + j] = bf2f(hbuf[b*168 + j]);
    }
}

// ================= classification head =================
__global__ __launch_bounds__(128) void rits_head(
    const float* __restrict__ probs, const float* __restrict__ ancillary, const int* __restrict__ labels,
    const float* __restrict__ W_anc, const float* __restrict__ b_anc,
    const float* __restrict__ b_cat,
    const float* __restrict__ W_out, const float* __restrict__ b_out,
    float* __restrict__ ws, float* __restrict__ out)
{
    __shared__ float hb[MB*H_];
    __shared__ float ancl[MB*52];
    __shared__ float hc[MB*H_];
    __shared__ float lg[MB*32];
    __shared__ float smx[MB], sinv[MB], ysum[MB];
    __shared__ float sq[MB*32];
    const int tid = threadIdx.x;
    const int bb0 = blockIdx.x * MB;

    for (int i = tid; i < MB*H_; i += 128) hb[i] = ws[WS_HFIN + (size_t)bb0*H_ + i];
    for (int i = tid; i < MB*E_; i += 128) {
        int b = i / E_, e = i - b*E_;
        float s = b_anc[e];
        #pragma unroll
        for (int a = 0; a < A_; ++a) s = fmaf(ancillary[(bb0+b)*A_ + a], W_anc[e*A_ + a], s);
        ancl[b*52+e] = fmaxf(s, 0.f);
    }
    __syncthreads();
    {
        const int j = tid;
        float s[MB];
        #pragma unroll
        for (int b = 0; b < MB; ++b) s[b] = b_cat[j];
        const float* wc = ws + WS_WCATT;
        for (int k = 0; k < H_; ++k) {
            float wv = wc[k*H_ + j];
            #pragma unroll
            for (int b = 0; b < MB; ++b) s[b] = fmaf(hb[b*H_+k], wv, s[b]);
        }
        for (int k = 0; k < E_; ++k) {
            float wv = wc[(H_+k)*H_ + j];
            #pragma unroll
            for (int b = 0; b < MB; ++b) s[b] = fmaf(ancl[b*52+k], wv, s[b]);
        }
        #pragma unroll
        for (int b = 0; b < MB; ++b) hc[b*H_+j] = fmaxf(s[b], 0.f);
    }
    __syncthreads();
    for (int i = tid; i < MB*O_; i += 128) {
        int b = i / O_, o = i - b*O_;
        float s = b_out[o];
        for (int k = 0; k < H_; ++k) s = fmaf(hc[b*H_+k], W_out[o*H_+k], s);
        lg[b*32+o] = s;
    }
    __syncthreads();
    if (tid < MB) {
        float mx = -1e30f;
        for (int o = 0; o < O_; ++o) mx = fmaxf(mx, lg[tid*32+o]);
        float se = 0.f;
        for (int o = 0; o < O_; ++o) se += __expf(lg[tid*32+o] - mx);
        smx[tid] = mx; sinv[tid] = 1.f / se;
    }
    __syncthreads();
    for (int i = tid; i < MB*O_; i += 128) {
        int b = i / O_, o = i - b*O_;
        float y = __expf(lg[b*32+o] - smx[b]) * sinv[b];
        out[OUT_YH + (size_t)(bb0+b)*O_ + o] = y;
        float d = y - probs[(size_t)(bb0+b)*O_ + o];
        sq[b*32+o] = d*d;
    }
    __syncthreads();
    if (tid < MB) {
        float s = 0.f;
        for (int o = 0; o < O_; ++o) s += sq[tid*32+o];
        ysum[tid] = s;
        out[OUT_LAB + bb0 + tid] = (float)labels[bb0 + tid];
    }
    __syncthreads();
    if (tid == 0) {
        float s = 0.f;
        #pragma unroll
        for (int b = 0; b < MB; ++b) s += ysum[b];
        atomicAdd(&ws[WS_ACC], s);
    }
}

// ================= finalize scalars =================
__global__ void rits_fin(const float* __restrict__ ws, float* __restrict__ out)
{
    if (blockIdx.x == 0 && threadIdx.x == 0) {
        float xl = 0.f;
        for (int t = 0; t < T_; ++t)
            xl += ws[WS_TACC + 2*t] / (ws[WS_TACC + 2*t + 1] + 1e-5f);
        xl *= 0.3f;
        float yl = ws[WS_ACC] * (1.0f / (8192.0f + 1e-5f));
        out[0] = xl; out[1] = yl; out[2] = xl + yl;
    }
}

extern "C" void kernel_launch(void* const* d_in, const int* in_sizes, int n_in,
                              void* d_out, int out_size, void* d_ws, size_t ws_size,
                              hipStream_t stream)
{
    const float* values = (const float*)d_in[0];
    const float* masks  = (const float*)d_in[1];
    const float* deltas = (const float*)d_in[2];
    const float* probs  = (const float*)d_in[3];
    const float* ancil  = (const float*)d_in[4];
    const int*   labels = (const int*)  d_in[5];
    const float* W_td_h = (const float*)d_in[6];
    const float* b_td_h = (const float*)d_in[7];
    const float* W_td_x = (const float*)d_in[8];
    const float* b_td_x = (const float*)d_in[9];
    const float* W_hist = (const float*)d_in[10];
    const float* b_hist = (const float*)d_in[11];
    const float* W_feat = (const float*)d_in[12];
    const float* b_feat = (const float*)d_in[13];
    const float* W_comb = (const float*)d_in[14];
    const float* b_comb = (const float*)d_in[15];
    const float* W_ih   = (const float*)d_in[16];
    const float* W_hh   = (const float*)d_in[17];
    const float* b_ih   = (const float*)d_in[18];
    const float* b_hh   = (const float*)d_in[19];
    const float* W_anc  = (const float*)d_in[20];
    const float* b_anc  = (const float*)d_in[21];
    const float* W_cat  = (const float*)d_in[22];
    const float* b_cat  = (const float*)d_in[23];
    const float* W_out  = (const float*)d_in[24];
    const float* b_out  = (const float*)d_in[25];
    float* ws  = (float*)d_ws;
    float* out = (float*)d_out;

    hipLaunchKernelGGL(rits_prep, dim3((H_*178 + 255)/256), dim3(256), 0, stream, W_cat, ws);
    hipLaunchKernelGGL(rits_main, dim3(B_/NB), dim3(NTHR), 0, stream,
                       values, masks, deltas, W_td_h, b_td_h, W_td_x, b_td_x,
                       W_hist, b_hist, W_feat, b_feat, W_comb, b_comb,
                       W_ih, W_hh, b_ih, b_hh, ws, out);
    hipLaunchKernelGGL(rits_head, dim3(B_/MB), dim3(128), 0, stream,
                       probs, ancil, labels, W_anc, b_anc, b_cat, W_out, b_out, ws, out);
    hipLaunchKernelGGL(rits_fin, dim3(1), dim3(1), 0, stream, ws, out);
}

// Round 5
// 1066.842 us; speedup vs baseline: 3.3994x; 3.3994x over previous
//
#include <hip/hip_runtime.h>
#include <hip/hip_bf16.h>
#include <math.h>

// ---------------- problem constants ----------------
#define B_ 8192
#define T_ 223
#define D_ 7
#define H_ 128
#define G_ 512      // 4*H
#define E_ 50
#define O_ 29
#define A_ 9
#define TD_ (T_*D_)     // 1561
#define NB 16           // batch rows per block (main) -> grid 512, 2 blocks/CU
#define NTHR 512
#define MB 8            // batch rows per block (head kernel)

// ---------------- workspace layout (float offsets) ----------------
#define WS_MINV  0                            // inv_t = 1/(msum_t+1e-5), T floats
#define WS_ACC   (WS_MINV + T_)               // [0]=x_loss raw sum, [1]=y_loss raw sum
#define WS_WCATT (WS_ACC + 2)                 // [178][128] transposed W_cat
#define WS_HFIN  (WS_WCATT + 178*H_)          // final h, [B][128] fp32
#define WS_MPART (WS_HFIN + B_*H_)            // [256][224] per-block mask-sum partials

// ---------------- output layout (floats) ----------------
#define OUT_YH  3
#define OUT_IMP (OUT_YH + B_*O_)              // 237571
#define OUT_LAB (OUT_IMP + B_*T_*D_)          // 13025283

typedef __attribute__((ext_vector_type(8))) short short8;   // 8 bf16 = 4 VGPRs
typedef __attribute__((ext_vector_type(4))) float floatx4;
#define MFMA16(Av,Bv,Cv) __builtin_amdgcn_mfma_f32_16x16x32_bf16((Av),(Bv),(Cv),0,0,0)

__device__ __forceinline__ unsigned short f2bf(float f) {   // RNE fp32->bf16
    __hip_bfloat16 h = __float2bfloat16(f);
    return __builtin_bit_cast(unsigned short, h);
}
__device__ __forceinline__ float bf2f(unsigned short s) {
    unsigned int u = ((unsigned int)s) << 16;
    return __builtin_bit_cast(float, u);
}
__device__ __forceinline__ float rcp_(float x)  { return __builtin_amdgcn_rcpf(x); }
__device__ __forceinline__ float sigm(float x)  { return rcp_(1.f + __expf(-x)); }
__device__ __forceinline__ float tanh_(float x) { return 1.f - 2.f*rcp_(1.f + __expf(2.f*x)); }

// ================= prep: W_cat transpose + zero accumulators =================
__global__ void rits_prep(const float* __restrict__ W_cat, float* __restrict__ ws)
{
    int idx = blockIdx.x * 256 + threadIdx.x;
    if (idx < H_*178) {                      // W_cat [128][178] -> [178][128]
        int j = idx / 178, k = idx - j*178;
        ws[WS_WCATT + k*H_ + j] = W_cat[idx];
    }
    if (idx < 2) ws[WS_ACC + idx] = 0.f;
}

// ================= coalesced per-step mask sums (partials) =================
// Block owns 32 batch rows; thread t sums masks[b][t][0..6] over those rows.
// Reads are fully coalesced (224 threads x 28B = one 6272B contiguous run per row).
__global__ __launch_bounds__(256) void rits_msum(const float* __restrict__ masks,
                                                 float* __restrict__ ws)
{
    const int t = threadIdx.x;
    const int b0 = blockIdx.x * 32;
    float s = 0.f;
    if (t < T_) {
        const float* p = masks + (size_t)b0*TD_ + t*D_;
        #pragma unroll 4
        for (int bb = 0; bb < 32; ++bb) {
            const float* q = p + (size_t)bb*TD_;
            #pragma unroll
            for (int e = 0; e < 7; ++e) s += q[e];
        }
        ws[WS_MPART + blockIdx.x*224 + t] = s;
    }
}

// ================= reduce partials -> inv_t =================
__global__ __launch_bounds__(256) void rits_minv(float* __restrict__ ws)
{
    const int t = threadIdx.x;
    if (t < T_) {
        float s = 0.f;
        #pragma unroll 8
        for (int blk = 0; blk < 256; ++blk) s += ws[WS_MPART + blk*224 + t];
        ws[WS_MINV + t] = rcp_(s + 1e-5f);
    }
}

// ================= main scan kernel (MFMA) =================
// D[gate j][batch b] = sum_k W_ext[j][k] * hext[b][k]
// A-frags (weights) persistent in VGPRs; B-frags (h / interleaved c_c,m) from LDS.
// Wave w owns gate M-tiles {w, 8+w, 16+w, 24+w} (one per i/f/g/o quadrant) so
// each lane's C rows give i,f,g,o for the SAME hidden j = w*16+quad*4+r.
// launch_bounds(512,2): VGPR cap 128 — weights (84 VGPRs) must NOT spill.
// 2 blocks/CU come from grid=512 + 128-VGPR HW occupancy, not from the bound.
__global__ __launch_bounds__(NTHR, 2) void rits_main(
    const float* __restrict__ values, const float* __restrict__ masks, const float* __restrict__ deltas,
    const float* __restrict__ W_td_h, const float* __restrict__ b_td_h,
    const float* __restrict__ W_td_x, const float* __restrict__ b_td_x,
    const float* __restrict__ W_hist, const float* __restrict__ b_hist,
    const float* __restrict__ W_feat, const float* __restrict__ b_feat,
    const float* __restrict__ W_comb, const float* __restrict__ b_comb,
    const float* __restrict__ W_ih, const float* __restrict__ W_hh,
    const float* __restrict__ b_ih, const float* __restrict__ b_hh,
    float* __restrict__ ws, float* __restrict__ out)
{
    // B-operand buffer: rows=batch(16), cols bf16: 0..127=h,
    // 128+2i=c_c[i], 129+2i=m[i] (i<7), 142..159=0. Row stride 168 bf16 = 336B.
    __shared__ __attribute__((aligned(16))) unsigned short hbuf[NB*168];
    __shared__ __attribute__((aligned(16))) unsigned short dbuf[NB*72];      // d(t+1) bf16, cols 7..31=0
    __shared__ __attribute__((aligned(16))) unsigned short whis_lds[16*136]; // W_hist bf16, rows 7..15=0
    __shared__ float xs[NB*8], msh[NB*8], dsl[NB*8];
    __shared__ float xh_l[NB*8], xc_l[NB*8], gx_l[NB*8];
    __shared__ float bhist_l[8], tdx_l[8], btdx_l[8];
    __shared__ float impbuf[NB*16*7];       // 16-step imputation buffer (fp32)
    __shared__ float red[8];

    const int tid  = threadIdx.x;
    const int b0   = blockIdx.x * NB;
    const int lane = tid & 63;
    const int w    = tid >> 6;      // wave 0..7
    const int quad = lane >> 4;
    const int l15  = lane & 15;

    // ---- one-time LDS init ----
    for (int i = tid; i < NB*168; i += NTHR) hbuf[i] = 0;
    for (int i = tid; i < NB*72;  i += NTHR) dbuf[i] = 0;
    for (int i = tid; i < 16*136; i += NTHR) {
        int r = i / 136, c = i - r*136;
        whis_lds[i] = (r < 7 && c < 128) ? f2bf(W_hist[r*H_ + c]) : 0;
    }
    if (tid < 8) {
        bhist_l[tid] = (tid < 7) ? b_hist[tid] : 0.f;
        tdx_l[tid]   = (tid < 7) ? W_td_x[tid*D_ + tid] : 0.f;
        btdx_l[tid]  = (tid < 7) ? b_td_x[tid] : 0.f;
    }

    // ---- persistent weight fragments (per lane) ----
    short8 whhf[4][4];   // [gate c][kstep]  A[j=l15 of tile][k=quad*8+e]
    short8 winf[4];      // ext kstep, interleaved: k=2i -> W_ih[j][i], k=2i+1 -> W_ih[j][7+i]
    short8 wtdf;         // W_td_h frag (j = w*16+l15, k<7)
    float  biasg_r[4][4];
    float  btdh_r[4];
    {
        union UU { short8 v; unsigned short u[8]; } fr;
        #pragma unroll
        for (int c = 0; c < 4; ++c) {
            const int j = (c*8 + w)*16 + l15;
            #pragma unroll
            for (int s = 0; s < 4; ++s) {
                const float* p = W_hh + j*H_ + s*32 + quad*8;
                #pragma unroll
                for (int e = 0; e < 8; ++e) fr.u[e] = f2bf(p[e]);
                whhf[c][s] = fr.v;
            }
            #pragma unroll
            for (int e = 0; e < 8; ++e) {
                int k = quad*8 + e;
                fr.u[e] = (k < 14) ? f2bf(W_ih[j*14 + (k >> 1) + ((k & 1) ? 7 : 0)])
                                   : (unsigned short)0;
            }
            winf[c] = fr.v;
            #pragma unroll
            for (int r = 0; r < 4; ++r) {
                int jj = (c*8 + w)*16 + quad*4 + r;
                biasg_r[c][r] = b_ih[jj] + b_hh[jj];
            }
        }
        #pragma unroll
        for (int e = 0; e < 8; ++e) {
            int k = quad*8 + e;
            fr.u[e] = (k < 7) ? f2bf(W_td_h[(w*16 + l15)*D_ + k]) : (unsigned short)0;
        }
        wtdf = fr.v;
        #pragma unroll
        for (int r = 0; r < 4; ++r) btdh_r[r] = b_td_h[w*16 + quad*4 + r];
    }

    // ---- A3 per-thread state ----
    const bool ldr = (tid < NB*D_);               // 112 threads (waves 0-1)
    const int  lb  = tid / D_, li = tid - (tid/D_)*D_;
    float wfr[7], wcr[14], bfr = 0.f, bcr = 0.f;
    if (ldr) {
        #pragma unroll
        for (int k = 0; k < 7; ++k)  wfr[k] = (k == li) ? 0.f : W_feat[li*D_ + k];
        #pragma unroll
        for (int k = 0; k < 14; ++k) wcr[k] = W_comb[li*14 + k];
        bfr = b_feat[li];  bcr = b_comb[li];
    }

    float c_st[4] = {0,0,0,0};
    float lacc = 0.f;

    // input prefetch (regs hold step-t data at loop top)
    const long gbase = (long)(b0 + lb)*TD_ + li;
    float rx = 0.f, rm = 0.f, rd = 0.f;
    if (ldr) { rx = values[gbase]; rm = masks[gbase]; rd = deltas[gbase]; }

    const float* minv = ws + WS_MINV;

    for (int t = 0; t < T_; ++t) {
        if (ldr) { xs[lb*8+li] = rx; msh[lb*8+li] = rm; dsl[lb*8+li] = rd; }
        __syncthreads();                       // [S] stage + prev h-writes visible
        if (ldr && t + 1 < T_) {
            const long g = gbase + (long)(t+1)*D_;
            rx = values[g]; rm = masks[g]; rd = deltas[g];
        }

        // ---- B1: gate h-part (+ x_h on wave 7). h in hbuf is ALREADY decayed ----
        floatx4 acc[4];
        #pragma unroll
        for (int c = 0; c < 4; ++c) {
            floatx4 a = { biasg_r[c][0], biasg_r[c][1], biasg_r[c][2], biasg_r[c][3] };
            acc[c] = a;
        }
        floatx4 xh0 = {0,0,0,0};
        #pragma unroll
        for (int s = 0; s < 4; ++s) {
            short8 hb0 = *(const short8*)&hbuf[l15*168 + s*32 + quad*8];
            #pragma unroll
            for (int c = 0; c < 4; ++c)
                acc[c] = MFMA16(whhf[c][s], hb0, acc[c]);
            if (w == 7) {
                short8 wh = *(const short8*)&whis_lds[l15*136 + s*32 + quad*8];
                xh0 = MFMA16(wh, hb0, xh0);
            }
        }
        // wave 7: finish x_h, compute x_c / gamma_x, publish to LDS
        if (w == 7 && quad < 2) {
            const int b = l15;
            #pragma unroll
            for (int r = 0; r < 4; ++r) {
                const int i = quad*4 + r;
                if (i < 7) {
                    float xhv = xh0[r] + bhist_l[i];
                    float x = xs[b*8+i], m = msh[b*8+i], d = dsl[b*8+i];
                    xh_l[b*8+i] = xhv;
                    xc_l[b*8+i] = m*x + (1.f-m)*xhv;
                    gx_l[b*8+i] = __expf(-fmaxf(fmaf(d, tdx_l[i], btdx_l[i]), 0.f));
                }
            }
        }
        __syncthreads();                       // [B] x_h / x_c / gamma_x ready

        // ---- A3: z_h, alpha, c_h, c_c, imputation, loss; write ext cols + dbuf ----
        if (ldr) {
            const int b = lb, i = li;
            const float invt = minv[t];
            const float x = xs[b*8+i], m = msh[b*8+i];
            float zh = bfr;
            #pragma unroll
            for (int k = 0; k < 7; ++k) zh = fmaf(wfr[k], xc_l[b*8+k], zh);
            float al = bcr;
            #pragma unroll
            for (int k = 0; k < 7; ++k) al = fmaf(wcr[k],   gx_l[b*8+k], al);
            #pragma unroll
            for (int k = 0; k < 7; ++k) al = fmaf(wcr[7+k], msh[b*8+k], al);
            const float xhv = xh_l[b*8+i];
            const float ch  = al*zh + (1.f-al)*xhv;
            const float cc  = m*x + (1.f-m)*ch;
            impbuf[(b*16 + (t & 15))*7 + i] = cc;
            *(unsigned int*)&hbuf[b*168 + 128 + 2*i] =
                (unsigned int)f2bf(cc) | ((unsigned int)f2bf(m) << 16);
            dbuf[b*72 + i] = f2bf(rd);         // d(t+1) for fused decay
            lacc = fmaf((fabsf(x-xhv) + fabsf(x-zh) + fabsf(x-ch)) * m, invt, lacc);
        }
        __syncthreads();                       // [C] c_c/m ext + dbuf ready

        // ---- B2: input part ----
        {
            short8 ib0 = *(const short8*)&hbuf[l15*168 + 128 + quad*8];
            #pragma unroll
            for (int c = 0; c < 4; ++c)
                acc[c] = MFMA16(winf[c], ib0, acc[c]);
        }
        // ---- fused gamma_h(t+1) via MFMA on d(t+1) ----
        floatx4 g0 = {0,0,0,0};
        const bool dec = (t + 1 < T_);
        if (dec) {
            short8 df0 = *(const short8*)&dbuf[l15*72 + quad*8];
            floatx4 z = {0,0,0,0};
            g0 = MFMA16(wtdf, df0, z);
        }
        // ---- LSTM update; write h (pre-decayed for next step) ----
        {
            const int b = l15;
            float hv[4];
            #pragma unroll
            for (int r = 0; r < 4; ++r) {
                float ig = acc[0][r], fg = acc[1][r];
                float gv = acc[2][r], og = acc[3][r];
                float cn = sigm(fg)*c_st[r] + sigm(ig)*tanh_(gv);
                c_st[r] = cn;
                float hn = sigm(og)*tanh_(cn);
                if (dec) hn *= __expf(-fmaxf(g0[r] + btdh_r[r], 0.f));
                hv[r] = hn;
            }
            uint2 pk;
            pk.x = (unsigned int)f2bf(hv[0]) | ((unsigned int)f2bf(hv[1]) << 16);
            pk.y = (unsigned int)f2bf(hv[2]) | ((unsigned int)f2bf(hv[3]) << 16);
            *(uint2*)&hbuf[b*168 + w*16 + quad*4] = pk;
        }

        // ---- imputation flush (contiguous 28B runs, 16 steps at a time) ----
        if ((t & 15) == 15 || t == T_ - 1) {
            const int t0 = t & ~15;
            if (tid < 256) {
                const int b = tid >> 4, c16 = tid & 15;
                if (t0 + c16 <= t) {
                    float* gp = out + (size_t)OUT_IMP + (size_t)(b0+b)*TD_ + (size_t)(t0+c16)*D_;
                    const float* lp = &impbuf[(b*16 + c16)*7];
                    #pragma unroll
                    for (int e = 0; e < 7; ++e) gp[e] = lp[e];
                }
            }
        }
    }
    __syncthreads();

    // ---- x_loss partial reduction ----
    for (int off = 32; off > 0; off >>= 1) lacc += __shfl_down(lacc, off, 64);
    if ((tid & 63) == 0) red[tid >> 6] = lacc;
    __syncthreads();
    if (tid == 0) {
        float s = 0.f;
        #pragma unroll
        for (int q = 0; q < 8; ++q) s += red[q];
        atomicAdd(&ws[WS_ACC], s);
    }
    // ---- final h -> workspace (fp32) ----
    for (int i = tid; i < NB*H_; i += NTHR) {
        int b = i >> 7, j = i & 127;
        ws[WS_HFIN + (size_t)(b0+b)*H_ + j] = bf2f(hbuf[b*168 + j]);
    }
}

// ================= classification head =================
__global__ __launch_bounds__(128) void rits_head(
    const float* __restrict__ probs, const float* __restrict__ ancillary, const int* __restrict__ labels,
    const float* __restrict__ W_anc, const float* __restrict__ b_anc,
    const float* __restrict__ b_cat,
    const float* __restrict__ W_out, const float* __restrict__ b_out,
    float* __restrict__ ws, float* __restrict__ out)
{
    __shared__ float hb[MB*H_];
    __shared__ float ancl[MB*52];
    __shared__ float hc[MB*H_];
    __shared__ float lg[MB*32];
    __shared__ float smx[MB], sinv[MB], ysum[MB];
    __shared__ float sq[MB*32];
    const int tid = threadIdx.x;
    const int bb0 = blockIdx.x * MB;

    for (int i = tid; i < MB*H_; i += 128) hb[i] = ws[WS_HFIN + (size_t)bb0*H_ + i];
    for (int i = tid; i < MB*E_; i += 128) {
        int b = i / E_, e = i - b*E_;
        float s = b_anc[e];
        #pragma unroll
        for (int a = 0; a < A_; ++a) s = fmaf(ancillary[(bb0+b)*A_ + a], W_anc[e*A_ + a], s);
        ancl[b*52+e] = fmaxf(s, 0.f);
    }
    __syncthreads();
    {
        const int j = tid;
        float s[MB];
        #pragma unroll
        for (int b = 0; b < MB; ++b) s[b] = b_cat[j];
        const float* wc = ws + WS_WCATT;
        for (int k = 0; k < H_; ++k) {
            float wv = wc[k*H_ + j];
            #pragma unroll
            for (int b = 0; b < MB; ++b) s[b] = fmaf(hb[b*H_+k], wv, s[b]);
        }
        for (int k = 0; k < E_; ++k) {
            float wv = wc[(H_+k)*H_ + j];
            #pragma unroll
            for (int b = 0; b < MB; ++b) s[b] = fmaf(ancl[b*52+k], wv, s[b]);
        }
        #pragma unroll
        for (int b = 0; b < MB; ++b) hc[b*H_+j] = fmaxf(s[b], 0.f);
    }
    __syncthreads();
    for (int i = tid; i < MB*O_; i += 128) {
        int b = i / O_, o = i - b*O_;
        float s = b_out[o];
        for (int k = 0; k < H_; ++k) s = fmaf(hc[b*H_+k], W_out[o*H_+k], s);
        lg[b*32+o] = s;
    }
    __syncthreads();
    if (tid < MB) {
        float mx = -1e30f;
        for (int o = 0; o < O_; ++o) mx = fmaxf(mx, lg[tid*32+o]);
        float se = 0.f;
        for (int o = 0; o < O_; ++o) se += __expf(lg[tid*32+o] - mx);
        smx[tid] = mx; sinv[tid] = 1.f / se;
    }
    __syncthreads();
    for (int i = tid; i < MB*O_; i += 128) {
        int b = i / O_, o = i - b*O_;
        float y = __expf(lg[b*32+o] - smx[b]) * sinv[b];
        out[OUT_YH + (size_t)(bb0+b)*O_ + o] = y;
        float d = y - probs[(size_t)(bb0+b)*O_ + o];
        sq[b*32+o] = d*d;
    }
    __syncthreads();
    if (tid < MB) {
        float s = 0.f;
        for (int o = 0; o < O_; ++o) s += sq[tid*32+o];
        ysum[tid] = s;
        out[OUT_LAB + bb0 + tid] = (float)labels[bb0 + tid];
    }
    __syncthreads();
    if (tid == 0) {
        float s = 0.f;
        #pragma unroll
        for (int b = 0; b < MB; ++b) s += ysum[b];
        atomicAdd(&ws[WS_ACC+1], s);
    }
}

// ================= finalize scalars =================
__global__ void rits_fin(const float* __restrict__ ws, float* __restrict__ out)
{
    if (blockIdx.x == 0 && threadIdx.x == 0) {
        float xl = ws[WS_ACC] * 0.3f;
        float yl = ws[WS_ACC+1] * (1.0f / (8192.0f + 1e-5f));
        out[0] = xl; out[1] = yl; out[2] = xl + yl;
    }
}

extern "C" void kernel_launch(void* const* d_in, const int* in_sizes, int n_in,
                              void* d_out, int out_size, void* d_ws, size_t ws_size,
                              hipStream_t stream)
{
    const float* values = (const float*)d_in[0];
    const float* masks  = (const float*)d_in[1];
    const float* deltas = (const float*)d_in[2];
    const float* probs  = (const float*)d_in[3];
    const float* ancil  = (const float*)d_in[4];
    const int*   labels = (const int*)  d_in[5];
    const float* W_td_h = (const float*)d_in[6];
    const float* b_td_h = (const float*)d_in[7];
    const float* W_td_x = (const float*)d_in[8];
    const float* b_td_x = (const float*)d_in[9];
    const float* W_hist = (const float*)d_in[10];
    const float* b_hist = (const float*)d_in[11];
    const float* W_feat = (const float*)d_in[12];
    const float* b_feat = (const float*)d_in[13];
    const float* W_comb = (const float*)d_in[14];
    const float* b_comb = (const float*)d_in[15];
    const float* W_ih   = (const float*)d_in[16];
    const float* W_hh   = (const float*)d_in[17];
    const float* b_ih   = (const float*)d_in[18];
    const float* b_hh   = (const float*)d_in[19];
    const float* W_anc  = (const float*)d_in[20];
    const float* b_anc  = (const float*)d_in[21];
    const float* W_cat  = (const float*)d_in[22];
    const float* b_cat  = (const float*)d_in[23];
    const float* W_out  = (const float*)d_in[24];
    const float* b_out  = (const float*)d_in[25];
    float* ws  = (float*)d_ws;
    float* out = (float*)d_out;

    hipLaunchKernelGGL(rits_prep, dim3((H_*178 + 255)/256), dim3(256), 0, stream, W_cat, ws);
    hipLaunchKernelGGL(rits_msum, dim3(256), dim3(256), 0, stream, masks, ws);
    hipLaunchKernelGGL(rits_minv, dim3(1), dim3(256), 0, stream, ws);
    hipLaunchKernelGGL(rits_main, dim3(B_/NB), dim3(NTHR), 0, stream,
                       values, masks, deltas, W_td_h, b_td_h, W_td_x, b_td_x,
                       W_hist, b_hist, W_feat, b_feat, W_comb, b_comb,
                       W_ih, W_hh, b_ih, b_hh, ws, out);
    hipLaunchKernelGGL(rits_head, dim3(B_/MB), dim3(128), 0, stream,
                       probs, ancil, labels, W_anc, b_anc, b_cat, W_out, b_out, ws, out);
    hipLaunchKernelGGL(rits_fin, dim3(1), dim3(1), 0, stream, ws, out);
}